// Round 10
// baseline (315.677 us; speedup 1.0000x reference)
//
#include <hip/hip_runtime.h>

// GCN: h' = relu(A @ (h @ W) + b) x3, last layer no relu.
// Per call: padded-bucket edge binning (partition w/ block-batched global
// reservation -> within-bucket sort emitting per-node begend), then:
// gemm0 (fp32 x -> bf16 sup), 3x fused [agg -> 16-node LDS tile -> MFMA
// gemm], final agg64. Agg loops: 16-edge batches = 4 row-gathers in flight
// per wave (latency hiding via MLP width), edge metas prefetched one batch
// ahead; invalid slots clamp to end-1 with zeroed weight (clamped loads all
// hit the same row -> cache-broadcast, ~free).

constexpr int NN = 50000;          // nodes
constexpr int NE = 800000;         // edges
constexpr int NB = (NN + 127) >> 7;          // 391 buckets (dst >> 7)
constexpr int CAP = 2560;                    // padded bucket capacity (mean 2046)
constexpr int PART_CHUNK = 4096;             // edges per partition block
constexpr int PART_GRID = (NE + PART_CHUNK - 1) / PART_CHUNK;  // 196

typedef __attribute__((ext_vector_type(8))) short bf16x8;
typedef __attribute__((ext_vector_type(4))) float floatx4;

__device__ inline unsigned short f2bf(float f) {          // RNE fp32->bf16
    unsigned u = __float_as_uint(f);
    u += 0x7fffu + ((u >> 16) & 1u);
    return (unsigned short)(u >> 16);
}
__device__ inline float bflo(unsigned v) { return __uint_as_float(v << 16); }
__device__ inline float bfhi(unsigned v) { return __uint_as_float(v & 0xffff0000u); }

// ---------------- binned edge sort (padded buckets, no pre-scan) ----------

__global__ __launch_bounds__(256) void k_part(
        const int* __restrict__ src, const int* __restrict__ dst,
        const float* __restrict__ w, int* __restrict__ bfill,
        int2* __restrict__ ep) {
    __shared__ int hist[NB], base[NB], off[NB];
    int tid = threadIdx.x;
    for (int b = tid; b < NB; b += 256) { hist[b] = 0; off[b] = 0; }
    __syncthreads();

    int e0 = blockIdx.x * PART_CHUNK;
    int  sreg[16]; int wreg[16]; short breg[16];
#pragma unroll
    for (int i = 0; i < 16; ++i) {
        int e = e0 + i * 256 + tid;
        if (e < NE) {
            int d = dst[e];
            int b = d >> 7;
            sreg[i] = (src[e] & 0xffff) | ((d & 127) << 16);
            wreg[i] = __float_as_int(w[e]);
            breg[i] = (short)b;
            atomicAdd(&hist[b], 1);
        } else breg[i] = -1;
    }
    __syncthreads();
    for (int b = tid; b < NB; b += 256)
        base[b] = b * CAP + atomicAdd(&bfill[b], hist[b]);
    __syncthreads();
#pragma unroll
    for (int i = 0; i < 16; ++i) {
        if (breg[i] >= 0) {
            int b = breg[i];
            int p = atomicAdd(&off[b], 1);
            ep[base[b] + p] = make_int2(sreg[i], wreg[i]);
        }
    }
}

__global__ __launch_bounds__(256) void k_sort(
        const int2* __restrict__ ep, const int* __restrict__ bfill,
        int2* __restrict__ es, int2* __restrict__ begend) {
    __shared__ int cnt[128], base[128], fl[128];
    int b  = blockIdx.x;
    int n0 = b << 7;
    int nn = min(128, NN - n0);
    int t  = threadIdx.x;
    if (t < 128) { cnt[t] = 0; fl[t] = 0; }
    __syncthreads();
    int beg = b * CAP, end = beg + bfill[b];
    for (int e = beg + t; e < end; e += 256)
        atomicAdd(&cnt[(ep[e].x >> 16) & 127], 1);
    __syncthreads();
    if (t < 128) base[t] = cnt[t];
    __syncthreads();
    for (int off = 1; off < 128; off <<= 1) {
        int add = (t >= off && t < 128) ? base[t - off] : 0;
        __syncthreads();
        if (t < 128) base[t] += add;     // inclusive scan
        __syncthreads();
    }
    if (t < nn) begend[n0 + t] = make_int2(beg + base[t] - cnt[t], beg + base[t]);
    __syncthreads();
    for (int e = beg + t; e < end; e += 256) {
        int2 v = ep[e];
        int d = (v.x >> 16) & 127;
        int pos = beg + base[d] - cnt[d] + atomicAdd(&fl[d], 1);
        es[pos] = make_int2(v.x & 0xffff, v.y);
    }
}

// ---------------- weight transpose+convert + bfill zero --------------------

__global__ void k_prep(
        const float* __restrict__ W0, const float* __restrict__ W1,
        const float* __restrict__ W2, const float* __restrict__ W3,
        unsigned short* __restrict__ T0, unsigned short* __restrict__ T1,
        unsigned short* __restrict__ T2, unsigned short* __restrict__ T3,
        int* __restrict__ bfill) {
    int b = blockIdx.x;              // 0..448
    if (b == 448) {
        for (int i = threadIdx.x; i < NB; i += 128) bfill[i] = 0;
        return;
    }
    const float* W; unsigned short* T; int N, n;
    if (b < 128)      { W = W0; T = T0; N = 128; n = b; }
    else if (b < 256) { W = W1; T = T1; N = 128; n = b - 128; }
    else if (b < 384) { W = W2; T = T2; N = 128; n = b - 256; }
    else              { W = W3; T = T3; N = 64;  n = b - 384; }
    int k = threadIdx.x;             // 0..127
    T[n * 128 + k] = f2bf(W[(size_t)k * N + n]);
}

// ---------------- GEMM 0 (MFMA): sup = bf16(x @ W0), x fp32 ----------------

__device__ inline bf16x8 ldA_f32(const float* A, size_t off) {
    float4 u = *(const float4*)&A[off];
    float4 v = *(const float4*)&A[off + 4];
    bf16x8 r;
    r[0] = (short)f2bf(u.x); r[1] = (short)f2bf(u.y);
    r[2] = (short)f2bf(u.z); r[3] = (short)f2bf(u.w);
    r[4] = (short)f2bf(v.x); r[5] = (short)f2bf(v.y);
    r[6] = (short)f2bf(v.z); r[7] = (short)f2bf(v.w);
    return r;
}

__global__ __launch_bounds__(256) void k_gemm0(
        const float* __restrict__ A,            // [M][128] fp32
        const unsigned short* __restrict__ Wt,  // [128][128] bf16
        unsigned short* __restrict__ C,         // [M][128] bf16
        int M) {
    constexpr int STR = 136;
    __shared__ unsigned short sWt[128 * STR];

    const int tid = threadIdx.x;
#pragma unroll
    for (int i = 0; i < 8; ++i) {
        int c = i * 256 + tid;
        int row = c >> 4, col = (c & 15) * 8;
        *(uint4*)&sWt[row * STR + col] = *(const uint4*)&Wt[row * 128 + col];
    }

    const int wv = tid >> 6;
    const int ln = tid & 63;
    const int m  = ln & 15;
    const int qd = ln >> 4;

    int gr  = blockIdx.x * 64 + wv * 16 + m;
    int grc = (gr < M) ? gr : (M - 1);
    bf16x8 af[4];
#pragma unroll
    for (int s = 0; s < 4; ++s)
        af[s] = ldA_f32(A, (size_t)grc * 128 + s * 32 + qd * 8);

    __syncthreads();

    floatx4 acc[8];
#pragma unroll
    for (int c = 0; c < 8; ++c) {
        acc[c] = (floatx4){0.f, 0.f, 0.f, 0.f};
#pragma unroll
        for (int s = 0; s < 4; ++s) {
            bf16x8 bf = *(const bf16x8*)&sWt[(c * 16 + m) * STR + s * 32 + qd * 8];
            acc[c] = __builtin_amdgcn_mfma_f32_16x16x32_bf16(af[s], bf, acc[c], 0, 0, 0);
        }
    }

    int row0 = blockIdx.x * 64 + wv * 16 + qd * 4;
#pragma unroll
    for (int c = 0; c < 8; ++c)
#pragma unroll
        for (int r = 0; r < 4; ++r) {
            int row = row0 + r;
            if (row < M) C[(size_t)row * 128 + c * 16 + m] = f2bf(acc[c][r]);
        }
}

// ---------------- Fused agg(layer i) + GEMM(layer i+1) ---------------------
// 16-node tile, 128 threads = 2 waves, 8 nodes per wave. Agg: 4 groups of
// 16 lanes; 16-edge batches = 4 row-gathers issued back-to-back (4 gathers
// in flight per wave), next batch's 4 metas prefetched before the FMA block.
// shfl_xor(16,32) combines; relu+bias -> bf16 tile in LDS. GEMM: wave =
// N-half; B-fragments straight from L2-hot Wt.

#define FMA8(W, R)                                                              \
    acc[0] = fmaf(W, bflo((R).x), acc[0]); acc[1] = fmaf(W, bfhi((R).x), acc[1]); \
    acc[2] = fmaf(W, bflo((R).y), acc[2]); acc[3] = fmaf(W, bfhi((R).y), acc[3]); \
    acc[4] = fmaf(W, bflo((R).z), acc[4]); acc[5] = fmaf(W, bfhi((R).z), acc[5]); \
    acc[6] = fmaf(W, bflo((R).w), acc[6]); acc[7] = fmaf(W, bfhi((R).w), acc[7]);

template<int NOUT>
__global__ __launch_bounds__(128, 8) void k_fused(
        const unsigned short* __restrict__ sup,  // [NN][128] bf16
        const int2* __restrict__ begend, const int2* __restrict__ es,
        const float* __restrict__ bias,          // layer-i bias (relu applied)
        const unsigned short* __restrict__ Wt,   // [NOUT][128] bf16
        unsigned short* __restrict__ C,          // [M][NOUT] bf16
        int M) {
    constexpr int NT  = NOUT / 16;
    constexpr int STR = 136;
    __shared__ unsigned short hT[16 * STR];

    const int tid = threadIdx.x;
    const int wv  = tid >> 6;        // 0..1
    const int ln  = tid & 63;
    const int g   = ln >> 4;         // edge group 0..3
    const int l   = ln & 15;         // 8-col slot

    float bs[8];
#pragma unroll
    for (int f = 0; f < 8; ++f) bs[f] = bias[l * 8 + f];

    const int n0 = blockIdx.x * 16;
    int2 be = begend[n0 + wv * 8];

    for (int nn = 0; nn < 8; ++nn) {
        int n = n0 + wv * 8 + nn;
        int beg = be.x, end = be.y;
        if (nn < 7) be = begend[n + 1];          // prefetch next node's range
        float acc[8] = {0.f, 0.f, 0.f, 0.f, 0.f, 0.f, 0.f, 0.f};
        if (end > beg) {
            int e = beg;
            int2 m0 = es[min(e + g,      end - 1)];
            int2 m1 = es[min(e + 4 + g,  end - 1)];
            int2 m2 = es[min(e + 8 + g,  end - 1)];
            int2 m3 = es[min(e + 12 + g, end - 1)];
            for (;;) {
                uint4 r0 = *(const uint4*)&sup[(size_t)m0.x * 128 + l * 8];
                uint4 r1 = *(const uint4*)&sup[(size_t)m1.x * 128 + l * 8];
                uint4 r2 = *(const uint4*)&sup[(size_t)m2.x * 128 + l * 8];
                uint4 r3 = *(const uint4*)&sup[(size_t)m3.x * 128 + l * 8];
                float w0 = (e + g      < end) ? __int_as_float(m0.y) : 0.f;
                float w1 = (e + 4 + g  < end) ? __int_as_float(m1.y) : 0.f;
                float w2 = (e + 8 + g  < end) ? __int_as_float(m2.y) : 0.f;
                float w3 = (e + 12 + g < end) ? __int_as_float(m3.y) : 0.f;
                bool more = (e + 16) < end;
                if (more) {
                    m0 = es[min(e + 16 + g, end - 1)];
                    m1 = es[min(e + 20 + g, end - 1)];
                    m2 = es[min(e + 24 + g, end - 1)];
                    m3 = es[min(e + 28 + g, end - 1)];
                }
                FMA8(w0, r0); FMA8(w1, r1); FMA8(w2, r2); FMA8(w3, r3);
                if (!more) break;
                e += 16;
            }
#pragma unroll
            for (int f = 0; f < 8; ++f) {
                acc[f] += __shfl_xor(acc[f], 16, 64);
                acc[f] += __shfl_xor(acc[f], 32, 64);
            }
        }
        if (g == 0) {
            unsigned pk[4];
#pragma unroll
            for (int q = 0; q < 4; ++q) {
                float a0 = fmaxf(acc[2 * q]     + bs[2 * q],     0.f);
                float a1 = fmaxf(acc[2 * q + 1] + bs[2 * q + 1], 0.f);
                pk[q] = (unsigned)f2bf(a0) | ((unsigned)f2bf(a1) << 16);
            }
            *(uint4*)&hT[(wv * 8 + nn) * STR + l * 8] = *(uint4*)pk;
        }
    }
    __syncthreads();

    // GEMM phase: wave = N-half. 16 rows x 64 cols per wave.
    const int m_ = ln & 15, qd = ln >> 4;
    const int c0 = wv * (NT / 2);
    bf16x8 af[4];
#pragma unroll
    for (int s = 0; s < 4; ++s)
        af[s] = *(const bf16x8*)&hT[m_ * STR + s * 32 + qd * 8];

    floatx4 acc2[NT / 2];
#pragma unroll
    for (int c = 0; c < NT / 2; ++c) {
        acc2[c] = (floatx4){0.f, 0.f, 0.f, 0.f};
#pragma unroll
        for (int s = 0; s < 4; ++s) {
            bf16x8 bf = *(const bf16x8*)&Wt[(size_t)((c0 + c) * 16 + m_) * 128 + s * 32 + qd * 8];
            acc2[c] = __builtin_amdgcn_mfma_f32_16x16x32_bf16(af[s], bf, acc2[c], 0, 0, 0);
        }
    }
    int row0 = n0 + qd * 4;
#pragma unroll
    for (int c = 0; c < NT / 2; ++c)
#pragma unroll
        for (int r = 0; r < 4; ++r) {
            int row = row0 + r;
            if (row < M) C[(size_t)row * NOUT + (c0 + c) * 16 + m_] = f2bf(acc2[c][r]);
        }
}

// ---------------- Final aggregate (layer 3): out fp32, no relu -------------
// 8 lanes per edge (16B/lane = 8 bf16 cols of the 64-col row), 32-edge
// batches = 4 row-gathers in flight; metas one batch ahead; shfl_xor(8,16,32).

__global__ __launch_bounds__(256) void k_agg64(
        const unsigned short* __restrict__ sup,  // [NN][64] bf16
        const int2* __restrict__ begend, const int2* __restrict__ es,
        const float* __restrict__ bias, float* __restrict__ out) {
    int n  = blockIdx.x * 4 + (threadIdx.x >> 6);
    int ln = threadIdx.x & 63;
    int g  = ln >> 3, l = ln & 7;
    int2 be = begend[n];
    int beg = be.x, end = be.y;
    float acc[8] = {0.f, 0.f, 0.f, 0.f, 0.f, 0.f, 0.f, 0.f};
    if (end > beg) {
        int e = beg;
        int2 m0 = es[min(e + g,      end - 1)];
        int2 m1 = es[min(e + 8 + g,  end - 1)];
        int2 m2 = es[min(e + 16 + g, end - 1)];
        int2 m3 = es[min(e + 24 + g, end - 1)];
        for (;;) {
            uint4 r0 = *(const uint4*)&sup[(size_t)m0.x * 64 + l * 8];
            uint4 r1 = *(const uint4*)&sup[(size_t)m1.x * 64 + l * 8];
            uint4 r2 = *(const uint4*)&sup[(size_t)m2.x * 64 + l * 8];
            uint4 r3 = *(const uint4*)&sup[(size_t)m3.x * 64 + l * 8];
            float w0 = (e + g      < end) ? __int_as_float(m0.y) : 0.f;
            float w1 = (e + 8 + g  < end) ? __int_as_float(m1.y) : 0.f;
            float w2 = (e + 16 + g < end) ? __int_as_float(m2.y) : 0.f;
            float w3 = (e + 24 + g < end) ? __int_as_float(m3.y) : 0.f;
            bool more = (e + 32) < end;
            if (more) {
                m0 = es[min(e + 32 + g, end - 1)];
                m1 = es[min(e + 40 + g, end - 1)];
                m2 = es[min(e + 48 + g, end - 1)];
                m3 = es[min(e + 56 + g, end - 1)];
            }
            FMA8(w0, r0); FMA8(w1, r1); FMA8(w2, r2); FMA8(w3, r3);
            if (!more) break;
            e += 32;
        }
    }
#pragma unroll
    for (int f = 0; f < 8; ++f) {
        acc[f] += __shfl_xor(acc[f], 8, 64);
        acc[f] += __shfl_xor(acc[f], 16, 64);
        acc[f] += __shfl_xor(acc[f], 32, 64);
    }
    if (g == 0) {
        float4 o0 = make_float4(acc[0] + bias[l * 8],     acc[1] + bias[l * 8 + 1],
                                acc[2] + bias[l * 8 + 2], acc[3] + bias[l * 8 + 3]);
        float4 o1 = make_float4(acc[4] + bias[l * 8 + 4], acc[5] + bias[l * 8 + 5],
                                acc[6] + bias[l * 8 + 6], acc[7] + bias[l * 8 + 7]);
        *(float4*)&out[(size_t)n * 64 + l * 8]     = o0;
        *(float4*)&out[(size_t)n * 64 + l * 8 + 4] = o1;
    }
}

// ---------------- launch ----------------

extern "C" void kernel_launch(void* const* d_in, const int* in_sizes, int n_in,
                              void* d_out, int out_size, void* d_ws, size_t ws_size,
                              hipStream_t stream) {
    (void)in_sizes; (void)n_in; (void)out_size; (void)ws_size;

    const float* x    = (const float*)d_in[0];
    const int*   esrc = (const int*)d_in[1];
    const int*   edst = (const int*)d_in[2];
    const float* ew   = (const float*)d_in[3];
    const float* W0   = (const float*)d_in[4];
    const float* b0   = (const float*)d_in[5];
    const float* W1   = (const float*)d_in[6];
    const float* b1   = (const float*)d_in[7];
    const float* W2   = (const float*)d_in[8];
    const float* b2   = (const float*)d_in[9];
    const float* W3   = (const float*)d_in[10];
    const float* b3   = (const float*)d_in[11];

    char* p = (char*)d_ws;
    auto alloc = [&](size_t bytes) {
        char* r = p;
        p += (bytes + 511) & ~size_t(511);
        return r;
    };
    int*   bfill  = (int*)  alloc((size_t)NB * 4);
    int2*  begend = (int2*) alloc((size_t)NN * 8);
    int2*  ep     = (int2*) alloc((size_t)NB * CAP * 8);
    int2*  es     = (int2*) alloc((size_t)NB * CAP * 8);
    unsigned short* sA  = (unsigned short*)alloc((size_t)NN * 128 * 2);
    unsigned short* sB  = (unsigned short*)alloc((size_t)NN * 128 * 2);
    unsigned short* Wt0 = (unsigned short*)alloc((size_t)128 * 128 * 2);
    unsigned short* Wt1 = (unsigned short*)alloc((size_t)128 * 128 * 2);
    unsigned short* Wt2 = (unsigned short*)alloc((size_t)128 * 128 * 2);
    unsigned short* Wt3 = (unsigned short*)alloc((size_t)64 * 128 * 2);

    // --- weights + bfill zero, then binned edge sort + begend ---
    k_prep<<<449, 128, 0, stream>>>(W0, W1, W2, W3, Wt0, Wt1, Wt2, Wt3, bfill);
    k_part<<<PART_GRID, 256, 0, stream>>>(esrc, edst, ew, bfill, ep);
    k_sort<<<NB, 256, 0, stream>>>(ep, bfill, es, begend);

    const int g0_grid = (NN + 63) / 64;     // 782
    const int f_grid  = (NN + 15) / 16;     // 3125
    const int a_grid  = (NN + 3) / 4;       // 12500

    // layer 0 GEMM: sup = bf16(x @ W0)
    k_gemm0<<<g0_grid, 256, 0, stream>>>(x, Wt0, sA, NN);
    // fused: agg0(+b0,relu) -> gemm1
    k_fused<128><<<f_grid, 128, 0, stream>>>(sA, begend, es, b0, Wt1, sB, NN);
    // fused: agg1(+b1,relu) -> gemm2
    k_fused<128><<<f_grid, 128, 0, stream>>>(sB, begend, es, b1, Wt2, sA, NN);
    // fused: agg2(+b2,relu) -> gemm3 (NOUT=64)
    k_fused<64><<<f_grid, 128, 0, stream>>>(sA, begend, es, b2, Wt3, sB, NN);
    // final: agg3 + b3, no relu, fp32 out
    k_agg64<<<a_grid, 256, 0, stream>>>(sB, begend, es, b3, (float*)d_out);
}

// Round 11
// 263.732 us; speedup vs baseline: 1.1970x; 1.1970x over previous
//
#include <hip/hip_runtime.h>

// GCN: h' = relu(A @ (h @ W) + b) x3, last layer no relu.
// Per call: padded-bucket edge binning (partition w/ block-batched global
// reservation -> within-bucket sort emitting per-node begend), then:
// gemm0 (fp32 x -> bf16 sup), 3x fused [agg -> 16-node LDS tile -> MFMA
// gemm], final agg64. Agg loops: 16-edge batches = 4 row-gathers in flight
// per wave; metas prefetched one batch ahead. launch_bounds relaxed to
// (128,4)/(256,4) so the 4-wide pipeline fits in VGPRs WITHOUT scratch
// spills (round 10's (128,8) bound caused ~90MB/dispatch spill traffic).

constexpr int NN = 50000;          // nodes
constexpr int NE = 800000;         // edges
constexpr int NB = (NN + 127) >> 7;          // 391 buckets (dst >> 7)
constexpr int CAP = 2560;                    // padded bucket capacity (mean 2046)
constexpr int PART_CHUNK = 4096;             // edges per partition block
constexpr int PART_GRID = (NE + PART_CHUNK - 1) / PART_CHUNK;  // 196

typedef __attribute__((ext_vector_type(8))) short bf16x8;
typedef __attribute__((ext_vector_type(4))) float floatx4;

__device__ inline unsigned short f2bf(float f) {          // RNE fp32->bf16
    unsigned u = __float_as_uint(f);
    u += 0x7fffu + ((u >> 16) & 1u);
    return (unsigned short)(u >> 16);
}
__device__ inline float bflo(unsigned v) { return __uint_as_float(v << 16); }
__device__ inline float bfhi(unsigned v) { return __uint_as_float(v & 0xffff0000u); }

// ---------------- binned edge sort (padded buckets, no pre-scan) ----------

__global__ __launch_bounds__(256) void k_part(
        const int* __restrict__ src, const int* __restrict__ dst,
        const float* __restrict__ w, int* __restrict__ bfill,
        int2* __restrict__ ep) {
    __shared__ int hist[NB], base[NB], off[NB];
    int tid = threadIdx.x;
    for (int b = tid; b < NB; b += 256) { hist[b] = 0; off[b] = 0; }
    __syncthreads();

    int e0 = blockIdx.x * PART_CHUNK;
    int  sreg[16]; int wreg[16]; short breg[16];
#pragma unroll
    for (int i = 0; i < 16; ++i) {
        int e = e0 + i * 256 + tid;
        if (e < NE) {
            int d = dst[e];
            int b = d >> 7;
            sreg[i] = (src[e] & 0xffff) | ((d & 127) << 16);
            wreg[i] = __float_as_int(w[e]);
            breg[i] = (short)b;
            atomicAdd(&hist[b], 1);
        } else breg[i] = -1;
    }
    __syncthreads();
    for (int b = tid; b < NB; b += 256)
        base[b] = b * CAP + atomicAdd(&bfill[b], hist[b]);
    __syncthreads();
#pragma unroll
    for (int i = 0; i < 16; ++i) {
        if (breg[i] >= 0) {
            int b = breg[i];
            int p = atomicAdd(&off[b], 1);
            ep[base[b] + p] = make_int2(sreg[i], wreg[i]);
        }
    }
}

__global__ __launch_bounds__(256) void k_sort(
        const int2* __restrict__ ep, const int* __restrict__ bfill,
        int2* __restrict__ es, int2* __restrict__ begend) {
    __shared__ int cnt[128], base[128], fl[128];
    int b  = blockIdx.x;
    int n0 = b << 7;
    int nn = min(128, NN - n0);
    int t  = threadIdx.x;
    if (t < 128) { cnt[t] = 0; fl[t] = 0; }
    __syncthreads();
    int beg = b * CAP, end = beg + bfill[b];
    for (int e = beg + t; e < end; e += 256)
        atomicAdd(&cnt[(ep[e].x >> 16) & 127], 1);
    __syncthreads();
    if (t < 128) base[t] = cnt[t];
    __syncthreads();
    for (int off = 1; off < 128; off <<= 1) {
        int add = (t >= off && t < 128) ? base[t - off] : 0;
        __syncthreads();
        if (t < 128) base[t] += add;     // inclusive scan
        __syncthreads();
    }
    if (t < nn) begend[n0 + t] = make_int2(beg + base[t] - cnt[t], beg + base[t]);
    __syncthreads();
    for (int e = beg + t; e < end; e += 256) {
        int2 v = ep[e];
        int d = (v.x >> 16) & 127;
        int pos = beg + base[d] - cnt[d] + atomicAdd(&fl[d], 1);
        es[pos] = make_int2(v.x & 0xffff, v.y);
    }
}

// ---------------- weight transpose+convert + bfill zero --------------------

__global__ void k_prep(
        const float* __restrict__ W0, const float* __restrict__ W1,
        const float* __restrict__ W2, const float* __restrict__ W3,
        unsigned short* __restrict__ T0, unsigned short* __restrict__ T1,
        unsigned short* __restrict__ T2, unsigned short* __restrict__ T3,
        int* __restrict__ bfill) {
    int b = blockIdx.x;              // 0..448
    if (b == 448) {
        for (int i = threadIdx.x; i < NB; i += 128) bfill[i] = 0;
        return;
    }
    const float* W; unsigned short* T; int N, n;
    if (b < 128)      { W = W0; T = T0; N = 128; n = b; }
    else if (b < 256) { W = W1; T = T1; N = 128; n = b - 128; }
    else if (b < 384) { W = W2; T = T2; N = 128; n = b - 256; }
    else              { W = W3; T = T3; N = 64;  n = b - 384; }
    int k = threadIdx.x;             // 0..127
    T[n * 128 + k] = f2bf(W[(size_t)k * N + n]);
}

// ---------------- GEMM 0 (MFMA): sup = bf16(x @ W0), x fp32 ----------------

__device__ inline bf16x8 ldA_f32(const float* A, size_t off) {
    float4 u = *(const float4*)&A[off];
    float4 v = *(const float4*)&A[off + 4];
    bf16x8 r;
    r[0] = (short)f2bf(u.x); r[1] = (short)f2bf(u.y);
    r[2] = (short)f2bf(u.z); r[3] = (short)f2bf(u.w);
    r[4] = (short)f2bf(v.x); r[5] = (short)f2bf(v.y);
    r[6] = (short)f2bf(v.z); r[7] = (short)f2bf(v.w);
    return r;
}

__global__ __launch_bounds__(256) void k_gemm0(
        const float* __restrict__ A,            // [M][128] fp32
        const unsigned short* __restrict__ Wt,  // [128][128] bf16
        unsigned short* __restrict__ C,         // [M][128] bf16
        int M) {
    constexpr int STR = 136;
    __shared__ unsigned short sWt[128 * STR];

    const int tid = threadIdx.x;
#pragma unroll
    for (int i = 0; i < 8; ++i) {
        int c = i * 256 + tid;
        int row = c >> 4, col = (c & 15) * 8;
        *(uint4*)&sWt[row * STR + col] = *(const uint4*)&Wt[row * 128 + col];
    }

    const int wv = tid >> 6;
    const int ln = tid & 63;
    const int m  = ln & 15;
    const int qd = ln >> 4;

    int gr  = blockIdx.x * 64 + wv * 16 + m;
    int grc = (gr < M) ? gr : (M - 1);
    bf16x8 af[4];
#pragma unroll
    for (int s = 0; s < 4; ++s)
        af[s] = ldA_f32(A, (size_t)grc * 128 + s * 32 + qd * 8);

    __syncthreads();

    floatx4 acc[8];
#pragma unroll
    for (int c = 0; c < 8; ++c) {
        acc[c] = (floatx4){0.f, 0.f, 0.f, 0.f};
#pragma unroll
        for (int s = 0; s < 4; ++s) {
            bf16x8 bf = *(const bf16x8*)&sWt[(c * 16 + m) * STR + s * 32 + qd * 8];
            acc[c] = __builtin_amdgcn_mfma_f32_16x16x32_bf16(af[s], bf, acc[c], 0, 0, 0);
        }
    }

    int row0 = blockIdx.x * 64 + wv * 16 + qd * 4;
#pragma unroll
    for (int c = 0; c < 8; ++c)
#pragma unroll
        for (int r = 0; r < 4; ++r) {
            int row = row0 + r;
            if (row < M) C[(size_t)row * 128 + c * 16 + m] = f2bf(acc[c][r]);
        }
}

// ---------------- Fused agg(layer i) + GEMM(layer i+1) ---------------------
// 16-node tile, 128 threads = 2 waves, 8 nodes per wave. Agg: 4 groups of
// 16 lanes; 16-edge batches = 4 row-gathers issued back-to-back (4 gathers
// in flight per wave), next batch's 4 metas prefetched before the FMA block.
// shfl_xor(16,32) combines; relu+bias -> bf16 tile in LDS. GEMM: wave =
// N-half; B-fragments straight from L2-hot Wt.

#define FMA8(W, R)                                                              \
    acc[0] = fmaf(W, bflo((R).x), acc[0]); acc[1] = fmaf(W, bfhi((R).x), acc[1]); \
    acc[2] = fmaf(W, bflo((R).y), acc[2]); acc[3] = fmaf(W, bfhi((R).y), acc[3]); \
    acc[4] = fmaf(W, bflo((R).z), acc[4]); acc[5] = fmaf(W, bfhi((R).z), acc[5]); \
    acc[6] = fmaf(W, bflo((R).w), acc[6]); acc[7] = fmaf(W, bfhi((R).w), acc[7]);

template<int NOUT>
__global__ __launch_bounds__(128, 4) void k_fused(
        const unsigned short* __restrict__ sup,  // [NN][128] bf16
        const int2* __restrict__ begend, const int2* __restrict__ es,
        const float* __restrict__ bias,          // layer-i bias (relu applied)
        const unsigned short* __restrict__ Wt,   // [NOUT][128] bf16
        unsigned short* __restrict__ C,          // [M][NOUT] bf16
        int M) {
    constexpr int NT  = NOUT / 16;
    constexpr int STR = 136;
    __shared__ unsigned short hT[16 * STR];

    const int tid = threadIdx.x;
    const int wv  = tid >> 6;        // 0..1
    const int ln  = tid & 63;
    const int g   = ln >> 4;         // edge group 0..3
    const int l   = ln & 15;         // 8-col slot

    const int n0 = blockIdx.x * 16;
    int2 be = begend[n0 + wv * 8];

    for (int nn = 0; nn < 8; ++nn) {
        int n = n0 + wv * 8 + nn;
        int beg = be.x, end = be.y;
        if (nn < 7) be = begend[n + 1];          // prefetch next node's range
        float acc[8] = {0.f, 0.f, 0.f, 0.f, 0.f, 0.f, 0.f, 0.f};
        if (end > beg) {
            int e = beg;
            int2 m0 = es[min(e + g,      end - 1)];
            int2 m1 = es[min(e + 4 + g,  end - 1)];
            int2 m2 = es[min(e + 8 + g,  end - 1)];
            int2 m3 = es[min(e + 12 + g, end - 1)];
            for (;;) {
                uint4 r0 = *(const uint4*)&sup[(size_t)m0.x * 128 + l * 8];
                uint4 r1 = *(const uint4*)&sup[(size_t)m1.x * 128 + l * 8];
                uint4 r2 = *(const uint4*)&sup[(size_t)m2.x * 128 + l * 8];
                uint4 r3 = *(const uint4*)&sup[(size_t)m3.x * 128 + l * 8];
                float w0 = (e + g      < end) ? __int_as_float(m0.y) : 0.f;
                float w1 = (e + 4 + g  < end) ? __int_as_float(m1.y) : 0.f;
                float w2 = (e + 8 + g  < end) ? __int_as_float(m2.y) : 0.f;
                float w3 = (e + 12 + g < end) ? __int_as_float(m3.y) : 0.f;
                bool more = (e + 16) < end;
                if (more) {
                    m0 = es[min(e + 16 + g, end - 1)];
                    m1 = es[min(e + 20 + g, end - 1)];
                    m2 = es[min(e + 24 + g, end - 1)];
                    m3 = es[min(e + 28 + g, end - 1)];
                }
                FMA8(w0, r0); FMA8(w1, r1); FMA8(w2, r2); FMA8(w3, r3);
                if (!more) break;
                e += 16;
            }
#pragma unroll
            for (int f = 0; f < 8; ++f) {
                acc[f] += __shfl_xor(acc[f], 16, 64);
                acc[f] += __shfl_xor(acc[f], 32, 64);
            }
        }
        if (g == 0) {
            unsigned pk[4];
#pragma unroll
            for (int q = 0; q < 4; ++q) {
                float a0 = fmaxf(acc[2 * q]     + bias[l * 8 + 2 * q],     0.f);
                float a1 = fmaxf(acc[2 * q + 1] + bias[l * 8 + 2 * q + 1], 0.f);
                pk[q] = (unsigned)f2bf(a0) | ((unsigned)f2bf(a1) << 16);
            }
            *(uint4*)&hT[(wv * 8 + nn) * STR + l * 8] = *(uint4*)pk;
        }
    }
    __syncthreads();

    // GEMM phase: wave = N-half. 16 rows x 64 cols per wave.
    const int m_ = ln & 15, qd = ln >> 4;
    const int c0 = wv * (NT / 2);
    bf16x8 af[4];
#pragma unroll
    for (int s = 0; s < 4; ++s)
        af[s] = *(const bf16x8*)&hT[m_ * STR + s * 32 + qd * 8];

    floatx4 acc2[NT / 2];
#pragma unroll
    for (int c = 0; c < NT / 2; ++c) {
        acc2[c] = (floatx4){0.f, 0.f, 0.f, 0.f};
#pragma unroll
        for (int s = 0; s < 4; ++s) {
            bf16x8 bf = *(const bf16x8*)&Wt[(size_t)((c0 + c) * 16 + m_) * 128 + s * 32 + qd * 8];
            acc2[c] = __builtin_amdgcn_mfma_f32_16x16x32_bf16(af[s], bf, acc2[c], 0, 0, 0);
        }
    }
    int row0 = n0 + qd * 4;
#pragma unroll
    for (int c = 0; c < NT / 2; ++c)
#pragma unroll
        for (int r = 0; r < 4; ++r) {
            int row = row0 + r;
            if (row < M) C[(size_t)row * NOUT + (c0 + c) * 16 + m_] = f2bf(acc2[c][r]);
        }
}

// ---------------- Final aggregate (layer 3): out fp32, no relu -------------
// 8 lanes per edge (16B/lane = 8 bf16 cols of the 64-col row), 32-edge
// batches = 4 row-gathers in flight; metas one batch ahead; shfl_xor(8,16,32).

__global__ __launch_bounds__(256, 4) void k_agg64(
        const unsigned short* __restrict__ sup,  // [NN][64] bf16
        const int2* __restrict__ begend, const int2* __restrict__ es,
        const float* __restrict__ bias, float* __restrict__ out) {
    int n  = blockIdx.x * 4 + (threadIdx.x >> 6);
    int ln = threadIdx.x & 63;
    int g  = ln >> 3, l = ln & 7;
    int2 be = begend[n];
    int beg = be.x, end = be.y;
    float acc[8] = {0.f, 0.f, 0.f, 0.f, 0.f, 0.f, 0.f, 0.f};
    if (end > beg) {
        int e = beg;
        int2 m0 = es[min(e + g,      end - 1)];
        int2 m1 = es[min(e + 8 + g,  end - 1)];
        int2 m2 = es[min(e + 16 + g, end - 1)];
        int2 m3 = es[min(e + 24 + g, end - 1)];
        for (;;) {
            uint4 r0 = *(const uint4*)&sup[(size_t)m0.x * 64 + l * 8];
            uint4 r1 = *(const uint4*)&sup[(size_t)m1.x * 64 + l * 8];
            uint4 r2 = *(const uint4*)&sup[(size_t)m2.x * 64 + l * 8];
            uint4 r3 = *(const uint4*)&sup[(size_t)m3.x * 64 + l * 8];
            float w0 = (e + g      < end) ? __int_as_float(m0.y) : 0.f;
            float w1 = (e + 8 + g  < end) ? __int_as_float(m1.y) : 0.f;
            float w2 = (e + 16 + g < end) ? __int_as_float(m2.y) : 0.f;
            float w3 = (e + 24 + g < end) ? __int_as_float(m3.y) : 0.f;
            bool more = (e + 32) < end;
            if (more) {
                m0 = es[min(e + 32 + g, end - 1)];
                m1 = es[min(e + 40 + g, end - 1)];
                m2 = es[min(e + 48 + g, end - 1)];
                m3 = es[min(e + 56 + g, end - 1)];
            }
            FMA8(w0, r0); FMA8(w1, r1); FMA8(w2, r2); FMA8(w3, r3);
            if (!more) break;
            e += 32;
        }
    }
#pragma unroll
    for (int f = 0; f < 8; ++f) {
        acc[f] += __shfl_xor(acc[f], 8, 64);
        acc[f] += __shfl_xor(acc[f], 16, 64);
        acc[f] += __shfl_xor(acc[f], 32, 64);
    }
    if (g == 0) {
        float4 o0 = make_float4(acc[0] + bias[l * 8],     acc[1] + bias[l * 8 + 1],
                                acc[2] + bias[l * 8 + 2], acc[3] + bias[l * 8 + 3]);
        float4 o1 = make_float4(acc[4] + bias[l * 8 + 4], acc[5] + bias[l * 8 + 5],
                                acc[6] + bias[l * 8 + 6], acc[7] + bias[l * 8 + 7]);
        *(float4*)&out[(size_t)n * 64 + l * 8]     = o0;
        *(float4*)&out[(size_t)n * 64 + l * 8 + 4] = o1;
    }
}

// ---------------- launch ----------------

extern "C" void kernel_launch(void* const* d_in, const int* in_sizes, int n_in,
                              void* d_out, int out_size, void* d_ws, size_t ws_size,
                              hipStream_t stream) {
    (void)in_sizes; (void)n_in; (void)out_size; (void)ws_size;

    const float* x    = (const float*)d_in[0];
    const int*   esrc = (const int*)d_in[1];
    const int*   edst = (const int*)d_in[2];
    const float* ew   = (const float*)d_in[3];
    const float* W0   = (const float*)d_in[4];
    const float* b0   = (const float*)d_in[5];
    const float* W1   = (const float*)d_in[6];
    const float* b1   = (const float*)d_in[7];
    const float* W2   = (const float*)d_in[8];
    const float* b2   = (const float*)d_in[9];
    const float* W3   = (const float*)d_in[10];
    const float* b3   = (const float*)d_in[11];

    char* p = (char*)d_ws;
    auto alloc = [&](size_t bytes) {
        char* r = p;
        p += (bytes + 511) & ~size_t(511);
        return r;
    };
    int*   bfill  = (int*)  alloc((size_t)NB * 4);
    int2*  begend = (int2*) alloc((size_t)NN * 8);
    int2*  ep     = (int2*) alloc((size_t)NB * CAP * 8);
    int2*  es     = (int2*) alloc((size_t)NB * CAP * 8);
    unsigned short* sA  = (unsigned short*)alloc((size_t)NN * 128 * 2);
    unsigned short* sB  = (unsigned short*)alloc((size_t)NN * 128 * 2);
    unsigned short* Wt0 = (unsigned short*)alloc((size_t)128 * 128 * 2);
    unsigned short* Wt1 = (unsigned short*)alloc((size_t)128 * 128 * 2);
    unsigned short* Wt2 = (unsigned short*)alloc((size_t)128 * 128 * 2);
    unsigned short* Wt3 = (unsigned short*)alloc((size_t)64 * 128 * 2);

    // --- weights + bfill zero, then binned edge sort + begend ---
    k_prep<<<449, 128, 0, stream>>>(W0, W1, W2, W3, Wt0, Wt1, Wt2, Wt3, bfill);
    k_part<<<PART_GRID, 256, 0, stream>>>(esrc, edst, ew, bfill, ep);
    k_sort<<<NB, 256, 0, stream>>>(ep, bfill, es, begend);

    const int g0_grid = (NN + 63) / 64;     // 782
    const int f_grid  = (NN + 15) / 16;     // 3125
    const int a_grid  = (NN + 3) / 4;       // 12500

    // layer 0 GEMM: sup = bf16(x @ W0)
    k_gemm0<<<g0_grid, 256, 0, stream>>>(x, Wt0, sA, NN);
    // fused: agg0(+b0,relu) -> gemm1
    k_fused<128><<<f_grid, 128, 0, stream>>>(sA, begend, es, b0, Wt1, sB, NN);
    // fused: agg1(+b1,relu) -> gemm2
    k_fused<128><<<f_grid, 128, 0, stream>>>(sB, begend, es, b1, Wt2, sA, NN);
    // fused: agg2(+b2,relu) -> gemm3 (NOUT=64)
    k_fused<64><<<f_grid, 128, 0, stream>>>(sA, begend, es, b2, Wt3, sB, NN);
    // final: agg3 + b3, no relu, fp32 out
    k_agg64<<<a_grid, 256, 0, stream>>>(sB, begend, es, b3, (float*)d_out);
}

// Round 12
// 254.822 us; speedup vs baseline: 1.2388x; 1.0350x over previous
//
#include <hip/hip_runtime.h>

// GCN: h' = relu(A @ (h @ W) + b) x3, last layer no relu.
// Per call: padded-bucket edge binning -> per-node SENTINEL-PADDED (mult of
// 16) dst-sorted edge lists, 4B packed records (src16 | bf16(w)<<16), then:
// gemm0 (fp32 x -> bf16 sup), 3x fused [agg -> 16-node LDS tile -> MFMA
// gemm], final agg64. Agg inner loops: zero branches/clamps (sentinels carry
// w=0), one broadcast uint4 meta load + 4 row-gathers per 16-edge batch.

constexpr int NN = 50000;          // nodes
constexpr int NE = 800000;         // edges
constexpr int NB = (NN + 127) >> 7;          // 391 buckets (dst >> 7)
constexpr int CAP = 4608;                    // padded bucket capacity
constexpr int PART_CHUNK = 4096;             // edges per partition block
constexpr int PART_GRID = (NE + PART_CHUNK - 1) / PART_CHUNK;  // 196

typedef __attribute__((ext_vector_type(8))) short bf16x8;
typedef __attribute__((ext_vector_type(4))) float floatx4;

__device__ inline unsigned short f2bf(float f) {          // RNE fp32->bf16
    unsigned u = __float_as_uint(f);
    u += 0x7fffu + ((u >> 16) & 1u);
    return (unsigned short)(u >> 16);
}
__device__ inline float bflo(unsigned v) { return __uint_as_float(v << 16); }
__device__ inline float bfhi(unsigned v) { return __uint_as_float(v & 0xffff0000u); }

// ---------------- binned edge sort (padded buckets) ----------------

__global__ __launch_bounds__(256) void k_part(
        const int* __restrict__ src, const int* __restrict__ dst,
        const float* __restrict__ w, int* __restrict__ bfill,
        int2* __restrict__ ep) {
    __shared__ int hist[NB], base[NB], off[NB];
    int tid = threadIdx.x;
    for (int b = tid; b < NB; b += 256) { hist[b] = 0; off[b] = 0; }
    __syncthreads();

    int e0 = blockIdx.x * PART_CHUNK;
    int  sreg[16]; int wreg[16]; short breg[16];
#pragma unroll
    for (int i = 0; i < 16; ++i) {
        int e = e0 + i * 256 + tid;
        if (e < NE) {
            int d = dst[e];
            int b = d >> 7;
            sreg[i] = (src[e] & 0xffff) | ((d & 127) << 16);
            wreg[i] = __float_as_int(w[e]);
            breg[i] = (short)b;
            atomicAdd(&hist[b], 1);
        } else breg[i] = -1;
    }
    __syncthreads();
    for (int b = tid; b < NB; b += 256)
        base[b] = b * CAP + atomicAdd(&bfill[b], hist[b]);
    __syncthreads();
#pragma unroll
    for (int i = 0; i < 16; ++i) {
        if (breg[i] >= 0) {
            int b = breg[i];
            int p = atomicAdd(&off[b], 1);
            ep[base[b] + p] = make_int2(sreg[i], wreg[i]);
        }
    }
}

// Within-bucket dst sort with per-node padding to multiple of 16.
// Emits packed 4B records: src16 | bf16(w)<<16; pad slots are 0 (w=0).
__global__ __launch_bounds__(256) void k_sort(
        const int2* __restrict__ ep, const int* __restrict__ bfill,
        unsigned* __restrict__ es, int2* __restrict__ begend) {
    __shared__ int cnt[128], base[128], fl[128];
    __shared__ int s_total;
    int b  = blockIdx.x;
    int n0 = b << 7;
    int nn = min(128, NN - n0);
    int t  = threadIdx.x;
    if (t < 128) { cnt[t] = 0; fl[t] = 0; }
    __syncthreads();
    int bbase = b * CAP;
    int beg = bbase, end = bbase + bfill[b];
    for (int e = beg + t; e < end; e += 256)
        atomicAdd(&cnt[(ep[e].x >> 16) & 127], 1);
    __syncthreads();
    int cp = (t < 128) ? ((cnt[t] + 15) & ~15) : 0;
    if (t < 128) base[t] = cp;
    __syncthreads();
    for (int off = 1; off < 128; off <<= 1) {
        int add = (t >= off && t < 128) ? base[t - off] : 0;
        __syncthreads();
        if (t < 128) base[t] += add;     // inclusive scan of padded counts
        __syncthreads();
    }
    if (t == 127) s_total = base[127];
    __syncthreads();
    int total = s_total;
    // zero the padded region (+16 trailing sentinels for prefetch safety)
    for (int i = t; i < total + 16; i += 256) es[bbase + i] = 0u;
    if (t < nn) {
        int off = base[t] - cp;
        begend[n0 + t] = make_int2(bbase + off, bbase + off + cp);
    }
    __syncthreads();
    for (int e = beg + t; e < end; e += 256) {
        int2 v = ep[e];
        int d = (v.x >> 16) & 127;
        int off = base[d] - ((cnt[d] + 15) & ~15);
        int pos = bbase + off + atomicAdd(&fl[d], 1);
        es[pos] = (unsigned)(v.x & 0xffff) |
                  ((unsigned)f2bf(__int_as_float(v.y)) << 16);
    }
}

// ---------------- weight transpose+convert + bfill zero --------------------

__global__ void k_prep(
        const float* __restrict__ W0, const float* __restrict__ W1,
        const float* __restrict__ W2, const float* __restrict__ W3,
        unsigned short* __restrict__ T0, unsigned short* __restrict__ T1,
        unsigned short* __restrict__ T2, unsigned short* __restrict__ T3,
        int* __restrict__ bfill) {
    int b = blockIdx.x;              // 0..448
    if (b == 448) {
        for (int i = threadIdx.x; i < NB; i += 128) bfill[i] = 0;
        return;
    }
    const float* W; unsigned short* T; int N, n;
    if (b < 128)      { W = W0; T = T0; N = 128; n = b; }
    else if (b < 256) { W = W1; T = T1; N = 128; n = b - 128; }
    else if (b < 384) { W = W2; T = T2; N = 128; n = b - 256; }
    else              { W = W3; T = T3; N = 64;  n = b - 384; }
    int k = threadIdx.x;             // 0..127
    T[n * 128 + k] = f2bf(W[(size_t)k * N + n]);
}

// ---------------- GEMM 0 (MFMA): sup = bf16(x @ W0), x fp32 ----------------

__device__ inline bf16x8 ldA_f32(const float* A, size_t off) {
    float4 u = *(const float4*)&A[off];
    float4 v = *(const float4*)&A[off + 4];
    bf16x8 r;
    r[0] = (short)f2bf(u.x); r[1] = (short)f2bf(u.y);
    r[2] = (short)f2bf(u.z); r[3] = (short)f2bf(u.w);
    r[4] = (short)f2bf(v.x); r[5] = (short)f2bf(v.y);
    r[6] = (short)f2bf(v.z); r[7] = (short)f2bf(v.w);
    return r;
}

__global__ __launch_bounds__(256) void k_gemm0(
        const float* __restrict__ A,            // [M][128] fp32
        const unsigned short* __restrict__ Wt,  // [128][128] bf16
        unsigned short* __restrict__ C,         // [M][128] bf16
        int M) {
    constexpr int STR = 136;
    __shared__ unsigned short sWt[128 * STR];

    const int tid = threadIdx.x;
#pragma unroll
    for (int i = 0; i < 8; ++i) {
        int c = i * 256 + tid;
        int row = c >> 4, col = (c & 15) * 8;
        *(uint4*)&sWt[row * STR + col] = *(const uint4*)&Wt[row * 128 + col];
    }

    const int wv = tid >> 6;
    const int ln = tid & 63;
    const int m  = ln & 15;
    const int qd = ln >> 4;

    int gr  = blockIdx.x * 64 + wv * 16 + m;
    int grc = (gr < M) ? gr : (M - 1);
    bf16x8 af[4];
#pragma unroll
    for (int s = 0; s < 4; ++s)
        af[s] = ldA_f32(A, (size_t)grc * 128 + s * 32 + qd * 8);

    __syncthreads();

    floatx4 acc[8];
#pragma unroll
    for (int c = 0; c < 8; ++c) {
        acc[c] = (floatx4){0.f, 0.f, 0.f, 0.f};
#pragma unroll
        for (int s = 0; s < 4; ++s) {
            bf16x8 bf = *(const bf16x8*)&sWt[(c * 16 + m) * STR + s * 32 + qd * 8];
            acc[c] = __builtin_amdgcn_mfma_f32_16x16x32_bf16(af[s], bf, acc[c], 0, 0, 0);
        }
    }

    int row0 = blockIdx.x * 64 + wv * 16 + qd * 4;
#pragma unroll
    for (int c = 0; c < 8; ++c)
#pragma unroll
        for (int r = 0; r < 4; ++r) {
            int row = row0 + r;
            if (row < M) C[(size_t)row * 128 + c * 16 + m] = f2bf(acc[c][r]);
        }
}

// ---------------- Fused agg(layer i) + GEMM(layer i+1) ---------------------
// 16-node tile, 128 threads = 2 waves, 8 nodes per wave. Agg: 4 groups of
// 16 lanes; group g owns edges e+4g..e+4g+3 of each 16-edge batch; per batch
// ONE broadcast uint4 meta load + 4 row-gathers; zero branches (sentinel
// padding). shfl_xor(16,32) combines; relu+bias -> bf16 tile in LDS.
// GEMM: wave = N-half; B-fragments straight from L2-hot Wt.

#define FMA8(W, R)                                                              \
    acc[0] = fmaf(W, bflo((R).x), acc[0]); acc[1] = fmaf(W, bfhi((R).x), acc[1]); \
    acc[2] = fmaf(W, bflo((R).y), acc[2]); acc[3] = fmaf(W, bfhi((R).y), acc[3]); \
    acc[4] = fmaf(W, bflo((R).z), acc[4]); acc[5] = fmaf(W, bfhi((R).z), acc[5]); \
    acc[6] = fmaf(W, bflo((R).w), acc[6]); acc[7] = fmaf(W, bfhi((R).w), acc[7]);

template<int NOUT>
__global__ __launch_bounds__(128, 4) void k_fused(
        const unsigned short* __restrict__ sup,  // [NN][128] bf16
        const int2* __restrict__ begend, const unsigned* __restrict__ es,
        const float* __restrict__ bias,          // layer-i bias (relu applied)
        const unsigned short* __restrict__ Wt,   // [NOUT][128] bf16
        unsigned short* __restrict__ C,          // [M][NOUT] bf16
        int M) {
    constexpr int NT  = NOUT / 16;
    constexpr int STR = 136;
    __shared__ unsigned short hT[16 * STR];

    const int tid = threadIdx.x;
    const int wv  = tid >> 6;        // 0..1
    const int ln  = tid & 63;
    const int g   = ln >> 4;         // edge group 0..3
    const int l   = ln & 15;         // 8-col slot

    const int n0 = blockIdx.x * 16;
    int2 be = begend[n0 + wv * 8];

    for (int nn = 0; nn < 8; ++nn) {
        int n = n0 + wv * 8 + nn;
        int beg = be.x, endp = be.y;
        if (nn < 7) be = begend[n + 1];          // prefetch next node's range
        float acc[8] = {0.f, 0.f, 0.f, 0.f, 0.f, 0.f, 0.f, 0.f};
        if (endp > beg) {
            int e = beg;
            uint4 mv = *(const uint4*)&es[e + 4 * g];
            for (;;) {
                uint4 r0 = *(const uint4*)&sup[(size_t)(mv.x & 0xffffu) * 128 + l * 8];
                uint4 r1 = *(const uint4*)&sup[(size_t)(mv.y & 0xffffu) * 128 + l * 8];
                uint4 r2 = *(const uint4*)&sup[(size_t)(mv.z & 0xffffu) * 128 + l * 8];
                uint4 r3 = *(const uint4*)&sup[(size_t)(mv.w & 0xffffu) * 128 + l * 8];
                float w0 = bfhi(mv.x), w1 = bfhi(mv.y);
                float w2 = bfhi(mv.z), w3 = bfhi(mv.w);
                e += 16;
                bool more = e < endp;
                uint4 mn = *(const uint4*)&es[e + 4 * g];  // sentinel-safe
                FMA8(w0, r0); FMA8(w1, r1); FMA8(w2, r2); FMA8(w3, r3);
                mv = mn;
                if (!more) break;
            }
#pragma unroll
            for (int f = 0; f < 8; ++f) {
                acc[f] += __shfl_xor(acc[f], 16, 64);
                acc[f] += __shfl_xor(acc[f], 32, 64);
            }
        }
        if (g == 0) {
            unsigned pk[4];
#pragma unroll
            for (int q = 0; q < 4; ++q) {
                float a0 = fmaxf(acc[2 * q]     + bias[l * 8 + 2 * q],     0.f);
                float a1 = fmaxf(acc[2 * q + 1] + bias[l * 8 + 2 * q + 1], 0.f);
                pk[q] = (unsigned)f2bf(a0) | ((unsigned)f2bf(a1) << 16);
            }
            *(uint4*)&hT[(wv * 8 + nn) * STR + l * 8] = *(uint4*)pk;
        }
    }
    __syncthreads();

    // GEMM phase: wave = N-half. 16 rows x 64 cols per wave.
    const int m_ = ln & 15, qd = ln >> 4;
    const int c0 = wv * (NT / 2);
    bf16x8 af[4];
#pragma unroll
    for (int s = 0; s < 4; ++s)
        af[s] = *(const bf16x8*)&hT[m_ * STR + s * 32 + qd * 8];

    floatx4 acc2[NT / 2];
#pragma unroll
    for (int c = 0; c < NT / 2; ++c) {
        acc2[c] = (floatx4){0.f, 0.f, 0.f, 0.f};
#pragma unroll
        for (int s = 0; s < 4; ++s) {
            bf16x8 bf = *(const bf16x8*)&Wt[(size_t)((c0 + c) * 16 + m_) * 128 + s * 32 + qd * 8];
            acc2[c] = __builtin_amdgcn_mfma_f32_16x16x32_bf16(af[s], bf, acc2[c], 0, 0, 0);
        }
    }
    int row0 = n0 + qd * 4;
#pragma unroll
    for (int c = 0; c < NT / 2; ++c)
#pragma unroll
        for (int r = 0; r < 4; ++r) {
            int row = row0 + r;
            if (row < M) C[(size_t)row * NOUT + (c0 + c) * 16 + m_] = f2bf(acc2[c][r]);
        }
}

// ---------------- Final aggregate (layer 3): out fp32, no relu -------------
// 8 groups of 8 lanes; group g owns edges e+2g, e+2g+1 of each 16-edge batch;
// one broadcast uint2 meta + 2 row-gathers per batch; zero branches.

__global__ __launch_bounds__(256, 4) void k_agg64(
        const unsigned short* __restrict__ sup,  // [NN][64] bf16
        const int2* __restrict__ begend, const unsigned* __restrict__ es,
        const float* __restrict__ bias, float* __restrict__ out) {
    int n  = blockIdx.x * 4 + (threadIdx.x >> 6);
    int ln = threadIdx.x & 63;
    int g  = ln >> 3, l = ln & 7;
    int2 be = begend[n];
    int beg = be.x, endp = be.y;
    float acc[8] = {0.f, 0.f, 0.f, 0.f, 0.f, 0.f, 0.f, 0.f};
    if (endp > beg) {
        int e = beg;
        uint2 mv = *(const uint2*)&es[e + 2 * g];
        for (;;) {
            uint4 r0 = *(const uint4*)&sup[(size_t)(mv.x & 0xffffu) * 64 + l * 8];
            uint4 r1 = *(const uint4*)&sup[(size_t)(mv.y & 0xffffu) * 64 + l * 8];
            float w0 = bfhi(mv.x), w1 = bfhi(mv.y);
            e += 16;
            bool more = e < endp;
            uint2 mn = *(const uint2*)&es[e + 2 * g];  // sentinel-safe
            FMA8(w0, r0); FMA8(w1, r1);
            mv = mn;
            if (!more) break;
        }
    }
#pragma unroll
    for (int f = 0; f < 8; ++f) {
        acc[f] += __shfl_xor(acc[f], 8, 64);
        acc[f] += __shfl_xor(acc[f], 16, 64);
        acc[f] += __shfl_xor(acc[f], 32, 64);
    }
    if (g == 0) {
        float4 o0 = make_float4(acc[0] + bias[l * 8],     acc[1] + bias[l * 8 + 1],
                                acc[2] + bias[l * 8 + 2], acc[3] + bias[l * 8 + 3]);
        float4 o1 = make_float4(acc[4] + bias[l * 8 + 4], acc[5] + bias[l * 8 + 5],
                                acc[6] + bias[l * 8 + 6], acc[7] + bias[l * 8 + 7]);
        *(float4*)&out[(size_t)n * 64 + l * 8]     = o0;
        *(float4*)&out[(size_t)n * 64 + l * 8 + 4] = o1;
    }
}

// ---------------- launch ----------------

extern "C" void kernel_launch(void* const* d_in, const int* in_sizes, int n_in,
                              void* d_out, int out_size, void* d_ws, size_t ws_size,
                              hipStream_t stream) {
    (void)in_sizes; (void)n_in; (void)out_size; (void)ws_size;

    const float* x    = (const float*)d_in[0];
    const int*   esrc = (const int*)d_in[1];
    const int*   edst = (const int*)d_in[2];
    const float* ew   = (const float*)d_in[3];
    const float* W0   = (const float*)d_in[4];
    const float* b0   = (const float*)d_in[5];
    const float* W1   = (const float*)d_in[6];
    const float* b1   = (const float*)d_in[7];
    const float* W2   = (const float*)d_in[8];
    const float* b2   = (const float*)d_in[9];
    const float* W3   = (const float*)d_in[10];
    const float* b3   = (const float*)d_in[11];

    char* p = (char*)d_ws;
    auto alloc = [&](size_t bytes) {
        char* r = p;
        p += (bytes + 511) & ~size_t(511);
        return r;
    };
    int*      bfill  = (int*)     alloc((size_t)NB * 4);
    int2*     begend = (int2*)    alloc((size_t)NN * 8);
    int2*     ep     = (int2*)    alloc((size_t)NB * CAP * 8);
    unsigned* es     = (unsigned*)alloc((size_t)NB * CAP * 4);
    unsigned short* sA  = (unsigned short*)alloc((size_t)NN * 128 * 2);
    unsigned short* sB  = (unsigned short*)alloc((size_t)NN * 128 * 2);
    unsigned short* Wt0 = (unsigned short*)alloc((size_t)128 * 128 * 2);
    unsigned short* Wt1 = (unsigned short*)alloc((size_t)128 * 128 * 2);
    unsigned short* Wt2 = (unsigned short*)alloc((size_t)128 * 128 * 2);
    unsigned short* Wt3 = (unsigned short*)alloc((size_t)64 * 128 * 2);

    // --- weights + bfill zero, then binned edge sort + begend ---
    k_prep<<<449, 128, 0, stream>>>(W0, W1, W2, W3, Wt0, Wt1, Wt2, Wt3, bfill);
    k_part<<<PART_GRID, 256, 0, stream>>>(esrc, edst, ew, bfill, ep);
    k_sort<<<NB, 256, 0, stream>>>(ep, bfill, es, begend);

    const int g0_grid = (NN + 63) / 64;     // 782
    const int f_grid  = (NN + 15) / 16;     // 3125
    const int a_grid  = (NN + 3) / 4;       // 12500

    // layer 0 GEMM: sup = bf16(x @ W0)
    k_gemm0<<<g0_grid, 256, 0, stream>>>(x, Wt0, sA, NN);
    // fused: agg0(+b0,relu) -> gemm1
    k_fused<128><<<f_grid, 128, 0, stream>>>(sA, begend, es, b0, Wt1, sB, NN);
    // fused: agg1(+b1,relu) -> gemm2
    k_fused<128><<<f_grid, 128, 0, stream>>>(sB, begend, es, b1, Wt2, sA, NN);
    // fused: agg2(+b2,relu) -> gemm3 (NOUT=64)
    k_fused<64><<<f_grid, 128, 0, stream>>>(sA, begend, es, b2, Wt3, sB, NN);
    // final: agg3 + b3, no relu, fp32 out
    k_agg64<<<a_grid, 256, 0, stream>>>(sB, begend, es, b3, (float*)d_out);
}